// Round 8
// baseline (158.980 us; speedup 1.0000x reference)
//
#include <hip/hip_runtime.h>

#define BB 8
#define TT 512
#define DD 512
#define LL 24
#define WPB 8              // waves per block
#define LPW 3              // levels per wave (24 / 8)
#define NBLK (BB * TT)     // 4096
#define NPART (NBLK * WPB) // 32768 per-wave partials

typedef float vf4 __attribute__((ext_vector_type(4)));   // native vector: ok for nontemporal builtins

__global__ __launch_bounds__(512, 8) void hs_kernel(
    const float* __restrict__ x,
    const float* __restrict__ node_vecs,
    const int* __restrict__ paths,
    const int* __restrict__ codes,
    const int* __restrict__ mask,
    float* __restrict__ partials)
{
    const int bt   = blockIdx.x;     // 0 .. B*T-1
    const int tid  = threadIdx.x;
    const int lane = tid & 63;
    // scalarized wave index -> meta addresses provably wave-uniform -> s_load
    const int wave = __builtin_amdgcn_readfirstlane(tid >> 6);   // 0..7

    const int base = bt * LL + wave * LPW;

    // meta through the SCALAR cache (s_load): zero vector-miss-queue traffic
    int msk[LPW], cod[LPW], pth[LPW];
    #pragma unroll
    for (int j = 0; j < LPW; ++j) {
        msk[j] = mask[base + j];
        cod[j] = codes[base + j];
        pth[j] = paths[base + j];
    }

    // x row via normal (allocating) loads: real 8-wave L1 reuse per block
    const vf4* xg = (const vf4*)(x + (size_t)bt * DD);
    const vf4 b0 = xg[lane];
    const vf4 b1 = xg[lane + 64];

    // gathers: NONTEMPORAL (nt) loads — multiplicity ~1.5, no L1 value;
    // avoid TCP line allocation so the miss queue sustains more fills
    vf4 a0[LPW], a1[LPW];
    #pragma unroll
    for (int j = 0; j < LPW; ++j) {
        if (msk[j]) {
            const vf4* nv = (const vf4*)(node_vecs + (size_t)pth[j] * DD);
            a0[j] = __builtin_nontemporal_load(&nv[lane]);
            a1[j] = __builtin_nontemporal_load(&nv[lane + 64]);
        } else {
            a0[j] = (vf4)(0.0f);
            a1[j] = (vf4)(0.0f);
        }
    }

    float dot[LPW];
    #pragma unroll
    for (int j = 0; j < LPW; ++j) {
        dot[j] = a0[j].x * b0.x + a0[j].y * b0.y + a0[j].z * b0.z + a0[j].w * b0.w
               + a1[j].x * b1.x + a1[j].y * b1.y + a1[j].z * b1.z + a1[j].w * b1.w;
    }

    // 3 independent butterfly chains, interleaved (6 steps total depth)
    #pragma unroll
    for (int off = 32; off >= 1; off >>= 1) {
        #pragma unroll
        for (int j = 0; j < LPW; ++j)
            dot[j] += __shfl_xor(dot[j], off, 64);
    }

    float local = 0.0f;
    #pragma unroll
    for (int j = 0; j < LPW; ++j) {
        // z = -sign*dot = (2c-1)*dot ; nll = softplus(z), HW transcendentals
        const float z   = (2.0f * (float)cod[j] - 1.0f) * dot[j];
        const float e   = __expf(-fabsf(z));                  // v_exp_f32
        const float nll = fmaxf(z, 0.0f) + __logf(1.0f + e);  // v_log_f32
        local += msk[j] ? nll : 0.0f;
    }

    // per-wave store — write-once, nontemporal
    if (lane == 0) __builtin_nontemporal_store(local, &partials[bt * WPB + wave]);
}

__global__ __launch_bounds__(1024) void hs_reduce(
    const float* __restrict__ partials, float* __restrict__ out)
{
    const int tid  = threadIdx.x;
    const int lane = tid & 63;
    const int wave = tid >> 6;          // 0..15
    __shared__ float wsum[16];

    const vf4* p4 = (const vf4*)partials;   // 8192 vf4s
    float s = 0.0f;
    #pragma unroll
    for (int r = 0; r < 8; ++r) {       // 8 independent vector loads, one latency round
        const vf4 v = p4[tid + r * 1024];
        s += (v.x + v.y) + (v.z + v.w);
    }

    #pragma unroll
    for (int off = 32; off >= 1; off >>= 1)
        s += __shfl_xor(s, off, 64);

    if (lane == 0) wsum[wave] = s;
    __syncthreads();
    if (tid == 0) {
        float t = 0.0f;
        #pragma unroll
        for (int i = 0; i < 16; ++i) t += wsum[i];
        out[0] = t * (1.0f / (float)BB);
    }
}

extern "C" void kernel_launch(void* const* d_in, const int* in_sizes, int n_in,
                              void* d_out, int out_size, void* d_ws, size_t ws_size,
                              hipStream_t stream) {
    const float* x         = (const float*)d_in[0];
    const float* node_vecs = (const float*)d_in[1];
    const int*   paths     = (const int*)d_in[2];
    const int*   codes     = (const int*)d_in[3];
    const int*   mask      = (const int*)d_in[4];
    float*       out       = (float*)d_out;
    float*       partials  = (float*)d_ws;   // 32768 floats = 128 KB, all written each launch

    hs_kernel<<<NBLK, 512, 0, stream>>>(x, node_vecs, paths, codes, mask, partials);
    hs_reduce<<<1, 1024, 0, stream>>>(partials, out);
}